// Round 2
// baseline (219.735 us; speedup 1.0000x reference)
//
#include <hip/hip_runtime.h>
#include <hip/hip_fp16.h>

// Problem constants (from reference setup_inputs)
#define B_   2
#define C_   256
#define H_   200
#define W_   304
#define HW_  60800       // H_*W_
#define N_   512
#define OH_  7
#define OW_  7
#define POS_ 49          // OH_*OW_
#define CPB_ 12544       // C_*POS_  (outputs per box)

#define HC_   128        // channels per gather block (c-half)
#define HCPB_ 6272       // HC_*POS_ (outputs per half-box)
#define GP2_  132        // gather staging pitch (halves), 8B aligned

// ---------------------------------------------------------------------------
// Pass 1 v6: transpose + fp32->fp16: (B, C, HW) -> (B, HW, C).
// Tile = 128 hw x 256 c (FULL C per block) so each block writes a fully
// contiguous 64 KB span of fmT (store wave = 1024 B contiguous, 2 full rows).
// Reads: 256 channel-rows x 512 B bursts (two 128-c sweeps). LDS 64 KB,
// un-padded with XOR quad swizzle per 128-c half: q' = q ^ 2*((row>>2)&7).
// 2 blocks/CU (8 waves) — streaming kernel with 16 float4 in flight/wave.
// ---------------------------------------------------------------------------
__global__ __launch_bounds__(256) void transpose_f16_v6(
    const float* __restrict__ fm,   // (B, C, HW) fp32
    ushort* __restrict__ fmT)       // (B, HW, C) fp16 bits
{
    __shared__ ushort tile[128 * 256];   // [hw][c], 64 KB, swizzled quads

    const int blk = blockIdx.x;          // 0..949
    const int b   = blk / 475;
    const int hwT = blk - b * 475;       // 0..474
    const int hw0 = hwT * 128;

    const int t = threadIdx.x;

    const float* __restrict__ src = fm + (size_t)b * C_ * HW_ + hw0;

    // ---- two 128-c sweeps: load 4 patches of (4c x 4hw)/thread, convert,
    //      4x4 register transpose -> ds_write_b64 (swizzled within the half)
    #pragma unroll
    for (int h = 0; h < 2; ++h) {
        float4 rg[4][4];
        #pragma unroll
        for (int i = 0; i < 4; ++i) {
            const int p  = i * 256 + t;
            const int hq = p & 31;           // hw quad 0..31
            const int cq = p >> 5;           // c  quad 0..31 (within half)
            #pragma unroll
            for (int j = 0; j < 4; ++j)
                rg[i][j] = *(const float4*)(src + (size_t)(h * 128 + cq * 4 + j) * HW_ + hq * 4);
        }

        #pragma unroll
        for (int i = 0; i < 4; ++i) {
            const int p  = i * 256 + t;
            const int hq = p & 31;
            const int cq = p >> 5;
            const int qs = cq ^ ((hq & 7) << 1);   // f(row)=2*((row>>2)&7), row>>2==hq
            #pragma unroll
            for (int j2 = 0; j2 < 4; ++j2) {       // hw element within the quad
                const int row = hq * 4 + j2;
                ushort4 u;
                u.x = __half_as_ushort(__float2half_rn(((const float*)&rg[i][0])[j2]));
                u.y = __half_as_ushort(__float2half_rn(((const float*)&rg[i][1])[j2]));
                u.z = __half_as_ushort(__float2half_rn(((const float*)&rg[i][2])[j2]));
                u.w = __half_as_ushort(__float2half_rn(((const float*)&rg[i][3])[j2]));
                *(ushort4*)&tile[row * 256 + h * 128 + qs * 4] = u;
            }
        }
    }
    __syncthreads();

    // ---- store phase: 16B/lane; wave inst = 2 rows x 512 B = 1024 B
    //      contiguous; whole block = contiguous 64 KB of fmT.
    ushort* __restrict__ dst = fmT + ((size_t)(b * HW_ + hw0)) * C_;

    #pragma unroll
    for (int s = 0; s < 16; ++s) {
        const int g   = s * 256 + t;     // 0..4095
        const int row = g >> 5;          // 0..127
        const int m   = g & 31;          // ushort8 block within the 256-c row
        const int hh  = m >> 4;          // c-half
        const int ml  = m & 15;
        const int msw = hh * 16 + (ml ^ ((row >> 2) & 7));   // un-swizzle
        const uint4 v = *(const uint4*)&tile[row * 256 + msw * 8];
        *(uint4*)(dst + (size_t)row * C_ + m * 8) = v;
    }
}

// ---------------------------------------------------------------------------
// Pass 2 v3 (UNCHANGED): gather, split per channel-half. One block per
// (box, c-half): 2048 blocks, LDS 13 KB, pos loop fully unrolled.
// ---------------------------------------------------------------------------
__global__ __launch_bounds__(256) void gather_f16_v3(
    const ushort* __restrict__ fmT,   // (B, HW, C) fp16 bits
    const float* __restrict__ boxes,  // (B, N, 5)
    float* __restrict__ out)          // (B*N, C, 7, 7) fp32
{
    __shared__ int4   sOff[POS_];             // tap offsets (pre-scaled by C_)
    __shared__ float4 sWgt[POS_];             // weights with validity folded
    __shared__ ushort sVal[POS_ * GP2_];      // [pos][c_loc] fp16, 12.9 KB

    const int blk = blockIdx.x;       // 0 .. 2*B*N-1
    const int bn  = blk >> 1;         // box index
    const int ch  = blk & 1;          // c-half 0/1
    const int b   = bn >> 9;          // N_ = 512
    const int tid = threadIdx.x;

    if (tid < POS_) {
        const float* bx = boxes + (size_t)bn * 5;
        const float cx = bx[0], cy = bx[1], w = bx[2], h = bx[3], ang = bx[4];

        const float rad = -ang * 0.017453292519943295f;   // -pi/180
        const float cr = cosf(rad), sr = sinf(rad);

        const float a00 =  w * (1.0f / W_) * cr;
        const float a01 = -h * (1.0f / H_) * sr;
        const float a02 =  2.0f * cx * (1.0f / W_) - 1.0f;
        const float a10 =  w * (1.0f / W_) * sr;
        const float a11 =  h * (1.0f / H_) * cr;
        const float a12 =  2.0f * cy * (1.0f / H_) - 1.0f;

        const int py = tid / OW_;
        const int px = tid - py * OW_;
        const float xs = (2.0f * (float)px + 1.0f) / (float)OW_ - 1.0f;
        const float ys = (2.0f * (float)py + 1.0f) / (float)OH_ - 1.0f;

        const float gx = a00 * xs + a01 * ys + a02;
        const float gy = a10 * xs + a11 * ys + a12;

        const float ix = ((gx + 1.0f) * (float)W_ - 1.0f) * 0.5f;
        const float iy = ((gy + 1.0f) * (float)H_ - 1.0f) * 0.5f;

        const float x0f = floorf(ix), y0f = floorf(iy);
        const float wx1 = ix - x0f,  wy1 = iy - y0f;
        const float wx0 = 1.0f - wx1, wy0 = 1.0f - wy1;
        const float x1f = x0f + 1.0f, y1f = y0f + 1.0f;

        const float vx0 = (x0f >= 0.0f && x0f <= (float)(W_ - 1)) ? 1.0f : 0.0f;
        const float vx1 = (x1f >= 0.0f && x1f <= (float)(W_ - 1)) ? 1.0f : 0.0f;
        const float vy0 = (y0f >= 0.0f && y0f <= (float)(H_ - 1)) ? 1.0f : 0.0f;
        const float vy1 = (y1f >= 0.0f && y1f <= (float)(H_ - 1)) ? 1.0f : 0.0f;

        const int xi0 = (int)fminf(fmaxf(x0f, 0.0f), (float)(W_ - 1));
        const int xi1 = (int)fminf(fmaxf(x1f, 0.0f), (float)(W_ - 1));
        const int yi0 = (int)fminf(fmaxf(y0f, 0.0f), (float)(H_ - 1));
        const int yi1 = (int)fminf(fmaxf(y1f, 0.0f), (float)(H_ - 1));

        sOff[tid] = make_int4((yi0 * W_ + xi0) * C_, (yi0 * W_ + xi1) * C_,
                              (yi1 * W_ + xi0) * C_, (yi1 * W_ + xi1) * C_);
        sWgt[tid] = make_float4(wy0 * wx0 * (vy0 * vx0),
                                wy0 * wx1 * (vy0 * vx1),
                                wy1 * wx0 * (vy1 * vx0),
                                wy1 * wx1 * (vy1 * vx1));
    }
    __syncthreads();

    const int cl = (tid & 31) * 4;      // local channel 0..124 (ushort4)
    const int g  = tid >> 5;            // pos group 0..7

    const ushort* __restrict__ fb =
        fmT + (size_t)b * HW_ * C_ + (size_t)(ch * HC_) + cl;

    #pragma unroll
    for (int k = 0; k < 7; ++k) {
        const int pos = g + k * 8;      // g=0 gets 7 positions, others 6
        if (pos < POS_) {
            const int4   o  = sOff[pos];
            const float4 wv = sWgt[pos];

            const ushort4 q0 = *(const ushort4*)(fb + o.x);
            const ushort4 q1 = *(const ushort4*)(fb + o.y);
            const ushort4 q2 = *(const ushort4*)(fb + o.z);
            const ushort4 q3 = *(const ushort4*)(fb + o.w);

            ushort4 u;
            {
                const float a = wv.x * __half2float(__ushort_as_half(q0.x))
                              + wv.y * __half2float(__ushort_as_half(q1.x))
                              + wv.z * __half2float(__ushort_as_half(q2.x))
                              + wv.w * __half2float(__ushort_as_half(q3.x));
                u.x = __half_as_ushort(__float2half_rn(a));
            }
            {
                const float a = wv.x * __half2float(__ushort_as_half(q0.y))
                              + wv.y * __half2float(__ushort_as_half(q1.y))
                              + wv.z * __half2float(__ushort_as_half(q2.y))
                              + wv.w * __half2float(__ushort_as_half(q3.y));
                u.y = __half_as_ushort(__float2half_rn(a));
            }
            {
                const float a = wv.x * __half2float(__ushort_as_half(q0.z))
                              + wv.y * __half2float(__ushort_as_half(q1.z))
                              + wv.z * __half2float(__ushort_as_half(q2.z))
                              + wv.w * __half2float(__ushort_as_half(q3.z));
                u.z = __half_as_ushort(__float2half_rn(a));
            }
            {
                const float a = wv.x * __half2float(__ushort_as_half(q0.w))
                              + wv.y * __half2float(__ushort_as_half(q1.w))
                              + wv.z * __half2float(__ushort_as_half(q2.w))
                              + wv.w * __half2float(__ushort_as_half(q3.w));
                u.w = __half_as_ushort(__float2half_rn(a));
            }
            *(ushort4*)&sVal[pos * GP2_ + cl] = u;
        }
    }
    __syncthreads();

    // half-box output: 128 c x 49 pos = 6272 floats, contiguous per block
    float* __restrict__ ob = out + (size_t)bn * CPB_ + (size_t)(ch * HCPB_);

    #pragma unroll
    for (int it = 0; it < 7; ++it) {
        const int flat4 = it * 256 + tid;     // float4 index, < 1568
        if (flat4 < 1568) {
            const int base = flat4 * 4;
            float4 v;
            {
                const int f = base + 0; const int cc = f / POS_; const int pp = f - cc * POS_;
                v.x = __half2float(__ushort_as_half(sVal[pp * GP2_ + cc]));
            }
            {
                const int f = base + 1; const int cc = f / POS_; const int pp = f - cc * POS_;
                v.y = __half2float(__ushort_as_half(sVal[pp * GP2_ + cc]));
            }
            {
                const int f = base + 2; const int cc = f / POS_; const int pp = f - cc * POS_;
                v.z = __half2float(__ushort_as_half(sVal[pp * GP2_ + cc]));
            }
            {
                const int f = base + 3; const int cc = f / POS_; const int pp = f - cc * POS_;
                v.w = __half2float(__ushort_as_half(sVal[pp * GP2_ + cc]));
            }
            *(float4*)(ob + base) = v;        // coalesced 16B store
        }
    }
}

// ---------------------------------------------------------------------------
// Fallback (R0 kernel): direct gather from (B,C,H,W) fp32 — used only if the
// workspace is too small for the fp16 transposed feature map.
// ---------------------------------------------------------------------------
__global__ __launch_bounds__(256) void rroi_align_fallback(
    const float* __restrict__ fm,
    const float* __restrict__ boxes,
    float* __restrict__ out)
{
    __shared__ int4   sOff[POS_];
    __shared__ float4 sWgt[POS_];

    const int bn  = blockIdx.x;
    const int b   = bn >> 9;
    const int tid = threadIdx.x;

    if (tid < POS_) {
        const float* bx = boxes + (size_t)bn * 5;
        const float cx = bx[0], cy = bx[1], w = bx[2], h = bx[3], ang = bx[4];
        const float rad = -ang * 0.017453292519943295f;
        const float cr = cosf(rad), sr = sinf(rad);
        const float a00 =  w * (1.0f / W_) * cr;
        const float a01 = -h * (1.0f / H_) * sr;
        const float a02 =  2.0f * cx * (1.0f / W_) - 1.0f;
        const float a10 =  w * (1.0f / W_) * sr;
        const float a11 =  h * (1.0f / H_) * cr;
        const float a12 =  2.0f * cy * (1.0f / H_) - 1.0f;
        const int py = tid / OW_;
        const int px = tid - py * OW_;
        const float xs = (2.0f * (float)px + 1.0f) / (float)OW_ - 1.0f;
        const float ys = (2.0f * (float)py + 1.0f) / (float)OH_ - 1.0f;
        const float gx = a00 * xs + a01 * ys + a02;
        const float gy = a10 * xs + a11 * ys + a12;
        const float ix = ((gx + 1.0f) * (float)W_ - 1.0f) * 0.5f;
        const float iy = ((gy + 1.0f) * (float)H_ - 1.0f) * 0.5f;
        const float x0f = floorf(ix), y0f = floorf(iy);
        const float wx1 = ix - x0f,  wy1 = iy - y0f;
        const float wx0 = 1.0f - wx1, wy0 = 1.0f - wy1;
        const float x1f = x0f + 1.0f, y1f = y0f + 1.0f;
        const float vx0 = (x0f >= 0.0f && x0f <= (float)(W_ - 1)) ? 1.0f : 0.0f;
        const float vx1 = (x1f >= 0.0f && x1f <= (float)(W_ - 1)) ? 1.0f : 0.0f;
        const float vy0 = (y0f >= 0.0f && y0f <= (float)(H_ - 1)) ? 1.0f : 0.0f;
        const float vy1 = (y1f >= 0.0f && y1f <= (float)(H_ - 1)) ? 1.0f : 0.0f;
        const int xi0 = (int)fminf(fmaxf(x0f, 0.0f), (float)(W_ - 1));
        const int xi1 = (int)fminf(fmaxf(x1f, 0.0f), (float)(W_ - 1));
        const int yi0 = (int)fminf(fmaxf(y0f, 0.0f), (float)(H_ - 1));
        const int yi1 = (int)fminf(fmaxf(y1f, 0.0f), (float)(H_ - 1));
        sOff[tid] = make_int4(yi0 * W_ + xi0, yi0 * W_ + xi1,
                              yi1 * W_ + xi0, yi1 * W_ + xi1);
        sWgt[tid] = make_float4(wy0 * wx0 * (vy0 * vx0),
                                wy0 * wx1 * (vy0 * vx1),
                                wy1 * wx0 * (vy1 * vx0),
                                wy1 * wx1 * (vy1 * vx1));
    }
    __syncthreads();

    const float* __restrict__ fb = fm + (size_t)b * C_ * HW_;
    float* __restrict__ ob = out + (size_t)bn * CPB_;

    #pragma unroll 7
    for (int it = 0; it < POS_; ++it) {
        const int flat = it * 256 + tid;
        const int cc   = flat / POS_;
        const int pos  = flat - cc * POS_;
        const int4   o  = sOff[pos];
        const float4 wv = sWgt[pos];
        const float* __restrict__ plane = fb + (size_t)cc * HW_;
        ob[flat] = wv.x * plane[o.x] + wv.y * plane[o.y]
                 + wv.z * plane[o.z] + wv.w * plane[o.w];
    }
}

extern "C" void kernel_launch(void* const* d_in, const int* in_sizes, int n_in,
                              void* d_out, int out_size, void* d_ws, size_t ws_size,
                              hipStream_t stream) {
    const float* fm    = (const float*)d_in[0];
    const float* boxes = (const float*)d_in[1];
    float* out         = (float*)d_out;

    const size_t needed = (size_t)B_ * C_ * HW_ * sizeof(ushort);  // 62.3 MB

    if (ws_size >= needed) {
        ushort* fmT = (ushort*)d_ws;
        transpose_f16_v6<<<dim3(B_ * 475), dim3(256), 0, stream>>>(fm, fmT);
        gather_f16_v3<<<dim3(2 * B_ * N_), dim3(256), 0, stream>>>(fmT, boxes, out);
    } else {
        rroi_align_fallback<<<dim3(B_ * N_), dim3(256), 0, stream>>>(fm, boxes, out);
    }
}

// Round 3
// 218.535 us; speedup vs baseline: 1.0055x; 1.0055x over previous
//
#include <hip/hip_runtime.h>
#include <hip/hip_fp16.h>

// Problem constants (from reference setup_inputs)
#define B_   2
#define C_   256
#define H_   200
#define W_   304
#define HW_  60800       // H_*W_
#define N_   512
#define OH_  7
#define OW_  7
#define POS_ 49          // OH_*OW_
#define CPB_ 12544       // C_*POS_  (outputs per box)

#define HC_   128        // channels per gather block (c-half)
#define HCPB_ 6272       // HC_*POS_ (outputs per half-box)
#define GP2_  132        // gather staging pitch (halves), 8B aligned

// ---------------------------------------------------------------------------
// Pass 1 v7: transpose + fp32->fp16: (B, C, HW) -> (B, HW, C).
// Tile = 256 hw x 128 c. READ bursts double to 1024 B per channel row
// (one wave-load = 64 lanes x 16 B contiguous from a single row) — testing
// the DRAM-page-efficiency-of-reads theory; R2 proved write burst size
// (256 B vs 1024 B) is perf-neutral, so writes return to 256 B chunks.
// LDS 64 KB fp16 [256 hw][128 c], XOR quad swizzle qs = cq ^ 2*((row>>2)&7)
// (bijective per row). 2 blocks/CU, 8 waves/CU; 4 KB/wave in flight per
// sweep x 8 pipelined sweeps covers Little's-law (~22 KB/CU) easily.
// HW_ % 256 != 0: last hw tile overlaps previous by 128 rows (idempotent).
// ---------------------------------------------------------------------------
__global__ __launch_bounds__(256) void transpose_f16_v7(
    const float* __restrict__ fm,   // (B, C, HW) fp32
    ushort* __restrict__ fmT)       // (B, HW, C) fp16 bits
{
    __shared__ ushort tile[256 * 128];   // [hw][c_half], 64 KB, swizzled quads

    const int blk = blockIdx.x;          // 0..951
    const int b   = blk / 476;
    const int r0  = blk - b * 476;
    const int ch  = r0 / 238;            // c-half 0/1
    const int hwT = r0 - ch * 238;       // 0..237
    const int hw0 = (hwT < 237) ? hwT * 256 : (HW_ - 256);   // overlap tail

    const int t  = threadIdx.x;
    const int hq = t & 63;               // hw 16B-quad 0..63 (per-lane)
    const int cg = t >> 6;               // c group 0..3 (uniform per wave)

    const float* __restrict__ src =
        fm + ((size_t)(b * C_ + ch * HC_)) * HW_ + hw0;

    // ---- 8 sweeps: load 4 rows x 1 hw-quad/thread (wave = 1024 B from one
    //      row), convert, 4x4 register transpose -> ds_write_b64 (swizzled)
    #pragma unroll
    for (int s = 0; s < 8; ++s) {
        float4 rg[4];
        #pragma unroll
        for (int j = 0; j < 4; ++j) {
            const int c = s * 16 + cg * 4 + j;
            rg[j] = *(const float4*)(src + (size_t)c * HW_ + hq * 4);
        }
        const int cquad = s * 4 + cg;              // 0..31
        const int qs    = cquad ^ ((hq & 7) << 1); // (row>>2)&7 == hq&7
        #pragma unroll
        for (int j2 = 0; j2 < 4; ++j2) {           // hw element within quad
            const int row = hq * 4 + j2;           // 0..255
            ushort4 u;
            u.x = __half_as_ushort(__float2half_rn(((const float*)&rg[0])[j2]));
            u.y = __half_as_ushort(__float2half_rn(((const float*)&rg[1])[j2]));
            u.z = __half_as_ushort(__float2half_rn(((const float*)&rg[2])[j2]));
            u.w = __half_as_ushort(__float2half_rn(((const float*)&rg[3])[j2]));
            *(ushort4*)&tile[row * 128 + qs * 4] = u;
        }
    }
    __syncthreads();

    // ---- store phase: 16B/lane; wave = 4 rows x 256 B chunks (@512 B stride)
    ushort* __restrict__ dst =
        fmT + ((size_t)(b * HW_ + hw0)) * C_ + ch * HC_;

    #pragma unroll
    for (int s = 0; s < 16; ++s) {
        const int g   = s * 256 + t;     // 0..4095
        const int row = g >> 4;          // 0..255
        const int m   = g & 15;          // ushort8 chunk within the 128-c half
        const int msw = m ^ ((row >> 2) & 7);   // un-swizzle (chunk level)
        const uint4 v = *(const uint4*)&tile[row * 128 + msw * 8];
        *(uint4*)(dst + (size_t)row * C_ + m * 8) = v;
    }
}

// ---------------------------------------------------------------------------
// Pass 2 v3 (UNCHANGED): gather, split per channel-half. One block per
// (box, c-half): 2048 blocks, LDS 13 KB, pos loop fully unrolled.
// ---------------------------------------------------------------------------
__global__ __launch_bounds__(256) void gather_f16_v3(
    const ushort* __restrict__ fmT,   // (B, HW, C) fp16 bits
    const float* __restrict__ boxes,  // (B, N, 5)
    float* __restrict__ out)          // (B*N, C, 7, 7) fp32
{
    __shared__ int4   sOff[POS_];             // tap offsets (pre-scaled by C_)
    __shared__ float4 sWgt[POS_];             // weights with validity folded
    __shared__ ushort sVal[POS_ * GP2_];      // [pos][c_loc] fp16, 12.9 KB

    const int blk = blockIdx.x;       // 0 .. 2*B*N-1
    const int bn  = blk >> 1;         // box index
    const int ch  = blk & 1;          // c-half 0/1
    const int b   = bn >> 9;          // N_ = 512
    const int tid = threadIdx.x;

    if (tid < POS_) {
        const float* bx = boxes + (size_t)bn * 5;
        const float cx = bx[0], cy = bx[1], w = bx[2], h = bx[3], ang = bx[4];

        const float rad = -ang * 0.017453292519943295f;   // -pi/180
        const float cr = cosf(rad), sr = sinf(rad);

        const float a00 =  w * (1.0f / W_) * cr;
        const float a01 = -h * (1.0f / H_) * sr;
        const float a02 =  2.0f * cx * (1.0f / W_) - 1.0f;
        const float a10 =  w * (1.0f / W_) * sr;
        const float a11 =  h * (1.0f / H_) * cr;
        const float a12 =  2.0f * cy * (1.0f / H_) - 1.0f;

        const int py = tid / OW_;
        const int px = tid - py * OW_;
        const float xs = (2.0f * (float)px + 1.0f) / (float)OW_ - 1.0f;
        const float ys = (2.0f * (float)py + 1.0f) / (float)OH_ - 1.0f;

        const float gx = a00 * xs + a01 * ys + a02;
        const float gy = a10 * xs + a11 * ys + a12;

        const float ix = ((gx + 1.0f) * (float)W_ - 1.0f) * 0.5f;
        const float iy = ((gy + 1.0f) * (float)H_ - 1.0f) * 0.5f;

        const float x0f = floorf(ix), y0f = floorf(iy);
        const float wx1 = ix - x0f,  wy1 = iy - y0f;
        const float wx0 = 1.0f - wx1, wy0 = 1.0f - wy1;
        const float x1f = x0f + 1.0f, y1f = y0f + 1.0f;

        const float vx0 = (x0f >= 0.0f && x0f <= (float)(W_ - 1)) ? 1.0f : 0.0f;
        const float vx1 = (x1f >= 0.0f && x1f <= (float)(W_ - 1)) ? 1.0f : 0.0f;
        const float vy0 = (y0f >= 0.0f && y0f <= (float)(H_ - 1)) ? 1.0f : 0.0f;
        const float vy1 = (y1f >= 0.0f && y1f <= (float)(H_ - 1)) ? 1.0f : 0.0f;

        const int xi0 = (int)fminf(fmaxf(x0f, 0.0f), (float)(W_ - 1));
        const int xi1 = (int)fminf(fmaxf(x1f, 0.0f), (float)(W_ - 1));
        const int yi0 = (int)fminf(fmaxf(y0f, 0.0f), (float)(H_ - 1));
        const int yi1 = (int)fminf(fmaxf(y1f, 0.0f), (float)(H_ - 1));

        sOff[tid] = make_int4((yi0 * W_ + xi0) * C_, (yi0 * W_ + xi1) * C_,
                              (yi1 * W_ + xi0) * C_, (yi1 * W_ + xi1) * C_);
        sWgt[tid] = make_float4(wy0 * wx0 * (vy0 * vx0),
                                wy0 * wx1 * (vy0 * vx1),
                                wy1 * wx0 * (vy1 * vx0),
                                wy1 * wx1 * (vy1 * vx1));
    }
    __syncthreads();

    const int cl = (tid & 31) * 4;      // local channel 0..124 (ushort4)
    const int g  = tid >> 5;            // pos group 0..7

    const ushort* __restrict__ fb =
        fmT + (size_t)b * HW_ * C_ + (size_t)(ch * HC_) + cl;

    #pragma unroll
    for (int k = 0; k < 7; ++k) {
        const int pos = g + k * 8;      // g=0 gets 7 positions, others 6
        if (pos < POS_) {
            const int4   o  = sOff[pos];
            const float4 wv = sWgt[pos];

            const ushort4 q0 = *(const ushort4*)(fb + o.x);
            const ushort4 q1 = *(const ushort4*)(fb + o.y);
            const ushort4 q2 = *(const ushort4*)(fb + o.z);
            const ushort4 q3 = *(const ushort4*)(fb + o.w);

            ushort4 u;
            {
                const float a = wv.x * __half2float(__ushort_as_half(q0.x))
                              + wv.y * __half2float(__ushort_as_half(q1.x))
                              + wv.z * __half2float(__ushort_as_half(q2.x))
                              + wv.w * __half2float(__ushort_as_half(q3.x));
                u.x = __half_as_ushort(__float2half_rn(a));
            }
            {
                const float a = wv.x * __half2float(__ushort_as_half(q0.y))
                              + wv.y * __half2float(__ushort_as_half(q1.y))
                              + wv.z * __half2float(__ushort_as_half(q2.y))
                              + wv.w * __half2float(__ushort_as_half(q3.y));
                u.y = __half_as_ushort(__float2half_rn(a));
            }
            {
                const float a = wv.x * __half2float(__ushort_as_half(q0.z))
                              + wv.y * __half2float(__ushort_as_half(q1.z))
                              + wv.z * __half2float(__ushort_as_half(q2.z))
                              + wv.w * __half2float(__ushort_as_half(q3.z));
                u.z = __half_as_ushort(__float2half_rn(a));
            }
            {
                const float a = wv.x * __half2float(__ushort_as_half(q0.w))
                              + wv.y * __half2float(__ushort_as_half(q1.w))
                              + wv.z * __half2float(__ushort_as_half(q2.w))
                              + wv.w * __half2float(__ushort_as_half(q3.w));
                u.w = __half_as_ushort(__float2half_rn(a));
            }
            *(ushort4*)&sVal[pos * GP2_ + cl] = u;
        }
    }
    __syncthreads();

    // half-box output: 128 c x 49 pos = 6272 floats, contiguous per block
    float* __restrict__ ob = out + (size_t)bn * CPB_ + (size_t)(ch * HCPB_);

    #pragma unroll
    for (int it = 0; it < 7; ++it) {
        const int flat4 = it * 256 + tid;     // float4 index, < 1568
        if (flat4 < 1568) {
            const int base = flat4 * 4;
            float4 v;
            {
                const int f = base + 0; const int cc = f / POS_; const int pp = f - cc * POS_;
                v.x = __half2float(__ushort_as_half(sVal[pp * GP2_ + cc]));
            }
            {
                const int f = base + 1; const int cc = f / POS_; const int pp = f - cc * POS_;
                v.y = __half2float(__ushort_as_half(sVal[pp * GP2_ + cc]));
            }
            {
                const int f = base + 2; const int cc = f / POS_; const int pp = f - cc * POS_;
                v.z = __half2float(__ushort_as_half(sVal[pp * GP2_ + cc]));
            }
            {
                const int f = base + 3; const int cc = f / POS_; const int pp = f - cc * POS_;
                v.w = __half2float(__ushort_as_half(sVal[pp * GP2_ + cc]));
            }
            *(float4*)(ob + base) = v;        // coalesced 16B store
        }
    }
}

// ---------------------------------------------------------------------------
// Fallback (R0 kernel): direct gather from (B,C,H,W) fp32 — used only if the
// workspace is too small for the fp16 transposed feature map.
// ---------------------------------------------------------------------------
__global__ __launch_bounds__(256) void rroi_align_fallback(
    const float* __restrict__ fm,
    const float* __restrict__ boxes,
    float* __restrict__ out)
{
    __shared__ int4   sOff[POS_];
    __shared__ float4 sWgt[POS_];

    const int bn  = blockIdx.x;
    const int b   = bn >> 9;
    const int tid = threadIdx.x;

    if (tid < POS_) {
        const float* bx = boxes + (size_t)bn * 5;
        const float cx = bx[0], cy = bx[1], w = bx[2], h = bx[3], ang = bx[4];
        const float rad = -ang * 0.017453292519943295f;
        const float cr = cosf(rad), sr = sinf(rad);
        const float a00 =  w * (1.0f / W_) * cr;
        const float a01 = -h * (1.0f / H_) * sr;
        const float a02 =  2.0f * cx * (1.0f / W_) - 1.0f;
        const float a10 =  w * (1.0f / W_) * sr;
        const float a11 =  h * (1.0f / H_) * cr;
        const float a12 =  2.0f * cy * (1.0f / H_) - 1.0f;
        const int py = tid / OW_;
        const int px = tid - py * OW_;
        const float xs = (2.0f * (float)px + 1.0f) / (float)OW_ - 1.0f;
        const float ys = (2.0f * (float)py + 1.0f) / (float)OH_ - 1.0f;
        const float gx = a00 * xs + a01 * ys + a02;
        const float gy = a10 * xs + a11 * ys + a12;
        const float ix = ((gx + 1.0f) * (float)W_ - 1.0f) * 0.5f;
        const float iy = ((gy + 1.0f) * (float)H_ - 1.0f) * 0.5f;
        const float x0f = floorf(ix), y0f = floorf(iy);
        const float wx1 = ix - x0f,  wy1 = iy - y0f;
        const float wx0 = 1.0f - wx1, wy0 = 1.0f - wy1;
        const float x1f = x0f + 1.0f, y1f = y0f + 1.0f;
        const float vx0 = (x0f >= 0.0f && x0f <= (float)(W_ - 1)) ? 1.0f : 0.0f;
        const float vx1 = (x1f >= 0.0f && x1f <= (float)(W_ - 1)) ? 1.0f : 0.0f;
        const float vy0 = (y0f >= 0.0f && y0f <= (float)(H_ - 1)) ? 1.0f : 0.0f;
        const float vy1 = (y1f >= 0.0f && y1f <= (float)(H_ - 1)) ? 1.0f : 0.0f;
        const int xi0 = (int)fminf(fmaxf(x0f, 0.0f), (float)(W_ - 1));
        const int xi1 = (int)fminf(fmaxf(x1f, 0.0f), (float)(W_ - 1));
        const int yi0 = (int)fminf(fmaxf(y0f, 0.0f), (float)(H_ - 1));
        const int yi1 = (int)fminf(fmaxf(y1f, 0.0f), (float)(H_ - 1));
        sOff[tid] = make_int4(yi0 * W_ + xi0, yi0 * W_ + xi1,
                              yi1 * W_ + xi0, yi1 * W_ + xi1);
        sWgt[tid] = make_float4(wy0 * wx0 * (vy0 * vx0),
                                wy0 * wx1 * (vy0 * vx1),
                                wy1 * wx0 * (vy1 * vx0),
                                wy1 * wx1 * (vy1 * vx1));
    }
    __syncthreads();

    const float* __restrict__ fb = fm + (size_t)b * C_ * HW_;
    float* __restrict__ ob = out + (size_t)bn * CPB_;

    #pragma unroll 7
    for (int it = 0; it < POS_; ++it) {
        const int flat = it * 256 + tid;
        const int cc   = flat / POS_;
        const int pos  = flat - cc * POS_;
        const int4   o  = sOff[pos];
        const float4 wv = sWgt[pos];
        const float* __restrict__ plane = fb + (size_t)cc * HW_;
        ob[flat] = wv.x * plane[o.x] + wv.y * plane[o.y]
                 + wv.z * plane[o.z] + wv.w * plane[o.w];
    }
}

extern "C" void kernel_launch(void* const* d_in, const int* in_sizes, int n_in,
                              void* d_out, int out_size, void* d_ws, size_t ws_size,
                              hipStream_t stream) {
    const float* fm    = (const float*)d_in[0];
    const float* boxes = (const float*)d_in[1];
    float* out         = (float*)d_out;

    const size_t needed = (size_t)B_ * C_ * HW_ * sizeof(ushort);  // 62.3 MB

    if (ws_size >= needed) {
        ushort* fmT = (ushort*)d_ws;
        transpose_f16_v7<<<dim3(B_ * 2 * 238), dim3(256), 0, stream>>>(fm, fmT);
        gather_f16_v3<<<dim3(2 * B_ * N_), dim3(256), 0, stream>>>(fmT, boxes, out);
    } else {
        rroi_align_fallback<<<dim3(B_ * N_), dim3(256), 0, stream>>>(fm, boxes, out);
    }
}